// Round 4
// baseline (340.754 us; speedup 1.0000x reference)
//
#include <hip/hip_runtime.h>
#include <hip/hip_bf16.h>

// Problem constants
#define S_LEN  1024
#define DMODEL 1024
#define NHEADS 16
#define DK     64
#define SCALE  0.125f
// rel table: 257 rows (padded to 272); rvT pitch 288.
// V layout (global): pair-tiled [bh][r/32][d][r%32] -> each 32-k V tile is a
// contiguous 4KB block, enabling coalesced global_load_lds staging.
// attn_fused (R3): ONE kernel replaces far+band. 2048 blocks x 128 thr
// (2 waves, one 16-row q-tile each). K/V double-buffered in LDS via
// global_load_lds (stage pc+1 issued BEFORE computing pc so the barrier's
// vmcnt drain hides under compute). All 64 k-tiles per wave: far tiles use
// c0/c1 clipped bias; band tiles compute the 16x32 bias block on the fly
// (8 MFMA, Q @ rel_k rows base-15..base+16, hi+lo) and resolve the j=r-l
// skew with two shfl per element. rel_v via per-wave w_s histogram
// + 8-chunk GEMM; e0/e1 rank-1 edges; direct normalize + ctx write.
// No OfarG/rsG round-trip, no separate qrel table.

typedef __bf16 bf16x8_t __attribute__((ext_vector_type(8)));
typedef __bf16 bf16x4_t __attribute__((ext_vector_type(4)));
typedef float  f32x4_t  __attribute__((ext_vector_type(4)));

#define MFMA16(A, B, C) __builtin_amdgcn_mfma_f32_16x16x32_bf16((A), (B), (C), 0, 0, 0)

__device__ __forceinline__ void async16(const void* g, void* l) {
    __builtin_amdgcn_global_load_lds(
        (const __attribute__((address_space(1))) unsigned int*)g,
        (__attribute__((address_space(3))) unsigned int*)l, 16, 0, 0);
}

// ---------------------------------------------------------------------------
// Kernel 1: cast inputs to bf16 + build padded rel tables.
__global__ __launch_bounds__(256) void cast_all_kernel(
    const float* __restrict__ q, const float* __restrict__ k, const float* __restrict__ v,
    const float* __restrict__ wq, const float* __restrict__ wk,
    const float* __restrict__ wv, const float* __restrict__ wo,
    const float* __restrict__ relk, const float* __restrict__ relv,
    __bf16* __restrict__ Xbf, __bf16* __restrict__ Wall,
    __bf16* __restrict__ relkp, __bf16* __restrict__ rvT,
    __bf16* __restrict__ Wqlo)
{
    const long i = (long)blockIdx.x * 256 + threadIdx.x;   // vec4 index
    if (i < 3145728) {                       // X region
        const int z   = (int)(i >> 20);
        const long rem = i & 1048575;
        const float4 s = ((const float4*)(z == 0 ? q : (z == 1 ? k : v)))[rem];
        bf16x4_t h;
        h[0] = (__bf16)s.x; h[1] = (__bf16)s.y; h[2] = (__bf16)s.z; h[3] = (__bf16)s.w;
        *(bf16x4_t*)(Xbf + ((size_t)z << 22) + rem * 4) = h;
    } else if (i < 3145728 + 1048576) {      // W region
        const long wi = i - 3145728;
        const int z   = (int)(wi >> 18);
        const long rem = wi & 262143;
        const float* src = (z == 0) ? wq : (z == 1) ? wk : (z == 2) ? wv : wo;
        const float4 s = ((const float4*)src)[rem];
        const float xs[4] = {s.x, s.y, s.z, s.w};
        bf16x4_t h;
        #pragma unroll
        for (int t = 0; t < 4; ++t) h[t] = (__bf16)xs[t];
        *(bf16x4_t*)(Wall + ((size_t)z << 20) + rem * 4) = h;
        if (z == 0) {
            bf16x4_t l;
            #pragma unroll
            for (int t = 0; t < 4; ++t) l[t] = (__bf16)(xs[t] - (float)h[t]);
            *(bf16x4_t*)(Wqlo + rem * 4) = l;
        }
    } else if (i < 3145728 + 1048576 + 4352) {   // relk hi+lo (272 rows x 64)
        const long ri = i - (3145728 + 1048576);
        const int j  = (int)(ri >> 4);
        const int d4 = (int)(ri & 15) * 4;
        bf16x4_t h, l;
        if (j < 257) {
            const float4 s = *(const float4*)(relk + j * 64 + d4);
            const float xs[4] = {s.x, s.y, s.z, s.w};
            #pragma unroll
            for (int t = 0; t < 4; ++t) {
                h[t] = (__bf16)xs[t];
                l[t] = (__bf16)(xs[t] - (float)h[t]);
            }
        } else {
            #pragma unroll
            for (int t = 0; t < 4; ++t) { h[t] = (__bf16)0.f; l[t] = (__bf16)0.f; }
        }
        *(bf16x4_t*)(relkp + j * 64 + d4) = h;
        *(bf16x4_t*)(relkp + 17408 + j * 64 + d4) = l;
    } else if (i < 3145728 + 1048576 + 4352 + 4608) { // rvT: [64][288], rvT[d][j]=rel_v[j][d]
        const long ri = i - (3145728 + 1048576 + 4352);
        const int d  = (int)(ri / 72);
        const int j4 = (int)(ri % 72) * 4;
        bf16x4_t o;
        #pragma unroll
        for (int t = 0; t < 4; ++t) {
            const int j = j4 + t;
            o[t] = (j < 257) ? (__bf16)relv[j * 64 + d] : (__bf16)0.f;
        }
        *(bf16x4_t*)(rvT + d * 288 + j4) = o;
    }
}

// ---------------------------------------------------------------------------
// Shared 128x128 tile GEMM core: acc += A(128xK) @ W(128xK)^T, K=1024, BK=32.
__device__ __forceinline__ void gemm128_core(
    const __bf16* __restrict__ A, const __bf16* __restrict__ W,
    __bf16* As, __bf16* Ws, f32x4_t acc[4][4])
{
    const int tid  = threadIdx.x;
    const int lane = tid & 63;
    const int quad = lane >> 4;
    const int l15  = lane & 15;
    const int wid  = tid >> 6;
    const int wm = wid >> 1, wn = wid & 1;

    for (int kt = 0; kt < 32; ++kt) {
        #pragma unroll
        for (int r = 0; r < 2; ++r) {
            const int c = r * 256 + tid;        // 512 chunks of 16B per tile
            const int row = c >> 2, kb = c & 3;
            async16(A + row * 1024 + kt * 32 + kb * 8, As + c * 8);
            async16(W + row * 1024 + kt * 32 + kb * 8, Ws + c * 8);
        }
        __syncthreads();
        bf16x8_t af[4], wf[4];
        #pragma unroll
        for (int i = 0; i < 4; ++i) {
            af[i] = *(const bf16x8_t*)(As + (wm * 64 + i * 16 + l15) * 32 + quad * 8);
            wf[i] = *(const bf16x8_t*)(Ws + (wn * 64 + i * 16 + l15) * 32 + quad * 8);
        }
        #pragma unroll
        for (int i = 0; i < 4; ++i)
            #pragma unroll
            for (int j = 0; j < 4; ++j)
                acc[i][j] = MFMA16(af[i], wf[j], acc[i][j]);
        __syncthreads();
    }
}

// ---------------------------------------------------------------------------
// Kernel 2: QKV projections. z=0:Q (W hi+lo), z=1:K [bh][s][d];
// z=2:V pair-tiled [bh][s/32][d][s%32].
__global__ __launch_bounds__(256) void gemm_qkv_kernel(
    const __bf16* __restrict__ Xbf, const __bf16* __restrict__ Wall,
    const __bf16* __restrict__ Wqlo,
    const float* __restrict__ bq, const float* __restrict__ bk, const float* __restrict__ bv,
    __bf16* __restrict__ QKVh)
{
    __shared__ __bf16 As[4096], Ws[4096];
    const int z = blockIdx.z;
    const __bf16* A = Xbf + (size_t)z * 4194304 + (size_t)blockIdx.y * 131072;
    const __bf16* W = Wall + (size_t)z * 1048576 + (size_t)blockIdx.x * 131072;
    f32x4_t acc[4][4];
    #pragma unroll
    for (int i = 0; i < 4; ++i)
        #pragma unroll
        for (int j = 0; j < 4; ++j)
            acc[i][j] = (f32x4_t){0.f, 0.f, 0.f, 0.f};

    gemm128_core(A, W, As, Ws, acc);
    if (z == 0)   // Q = Xhi*(Whi+Wlo)
        gemm128_core(A, Wqlo + (size_t)blockIdx.x * 131072, As, Ws, acc);

    const int tid = threadIdx.x, lane = tid & 63, quad = lane >> 4, l15 = lane & 15;
    const int wid = tid >> 6, wm = wid >> 1, wn = wid & 1;
    const int m0 = blockIdx.y * 128 + wm * 64;
    const int n0 = blockIdx.x * 128 + wn * 64;
    const float* bias = (z == 0) ? bq : ((z == 1) ? bk : bv);
    __bf16* dst = QKVh + (size_t)z * 4194304;

    if (z < 2) {
        #pragma unroll
        for (int j = 0; j < 4; ++j) {
            const int n = n0 + j * 16 + l15;
            const float bn = bias[n];
            #pragma unroll
            for (int i = 0; i < 4; ++i) {
                #pragma unroll
                for (int v = 0; v < 4; ++v) {
                    const int m = m0 + i * 16 + quad * 4 + v;
                    dst[((((m >> 10) * 16 + (n >> 6)) << 16)) + ((m & 1023) << 6) + (n & 63)]
                        = (__bf16)(acc[i][j][v] + bn);
                }
            }
        }
    } else {
        #pragma unroll
        for (int j = 0; j < 4; ++j) {
            const int n = n0 + j * 16 + l15;
            const float bn = bias[n];
            #pragma unroll
            for (int i = 0; i < 4; ++i) {
                const int m = m0 + i * 16 + quad * 4;
                bf16x4_t pk;
                #pragma unroll
                for (int v = 0; v < 4; ++v) pk[v] = (__bf16)(acc[i][j][v] + bn);
                const int s = m & 1023, d = n & 63;
                const size_t idx = (((size_t)((m >> 10) * 16 + (n >> 6))) << 16)
                                 + (size_t)(s >> 5) * 2048 + d * 32 + (s & 31);
                *(bf16x4_t*)(dst + idx) = pk;
            }
        }
    }
}

// ---------------------------------------------------------------------------
// Kernel 5: output projection, fp32 epilogue straight to d_out.
__global__ __launch_bounds__(256) void gemm_out_kernel(
    const __bf16* __restrict__ ctx, const __bf16* __restrict__ Wo,
    const float* __restrict__ bo, float* __restrict__ out)
{
    __shared__ __bf16 As[4096], Ws[4096];
    const __bf16* A = ctx + (size_t)blockIdx.y * 131072;
    const __bf16* W = Wo + (size_t)blockIdx.x * 131072;
    f32x4_t acc[4][4];
    #pragma unroll
    for (int i = 0; i < 4; ++i)
        #pragma unroll
        for (int j = 0; j < 4; ++j)
            acc[i][j] = (f32x4_t){0.f, 0.f, 0.f, 0.f};
    gemm128_core(A, W, As, Ws, acc);

    const int tid = threadIdx.x, lane = tid & 63, quad = lane >> 4, l15 = lane & 15;
    const int wid = tid >> 6, wm = wid >> 1, wn = wid & 1;
    const int m0 = blockIdx.y * 128 + wm * 64;
    const int n0 = blockIdx.x * 128 + wn * 64;
    #pragma unroll
    for (int j = 0; j < 4; ++j) {
        const int n = n0 + j * 16 + l15;
        const float bn = bo[n];
        #pragma unroll
        for (int i = 0; i < 4; ++i)
            #pragma unroll
            for (int v = 0; v < 4; ++v) {
                const int m = m0 + i * 16 + quad * 4 + v;
                out[(size_t)m * 1024 + n] = acc[i][j][v] + bn;
            }
    }
}

// ---------------------------------------------------------------------------
// Kernel 3: FUSED attention (far + band + rel_v), see header comment.
__global__ __launch_bounds__(128, 2) void attn_fused_kernel(
    const __bf16* __restrict__ Qh, const __bf16* __restrict__ Kh,
    const __bf16* __restrict__ Vt, const __bf16* __restrict__ relkp,
    const __bf16* __restrict__ rvT, const int* __restrict__ mask,
    const float* __restrict__ relv, __bf16* __restrict__ ctx)
{
    __shared__ __align__(16) __bf16 Ks[2][2048];     // 2 x (32r x 64d), swizzled
    __shared__ __align__(16) __bf16 Vs[2][2048];     // 2 x (64d x 32r), swizzled
    __shared__ __align__(16) __bf16 p_s[2][16][40];  // per-wave P staging
    __shared__ __align__(16) __bf16 w_s[2][16][272]; // per-wave rel_v histogram

    const int tid = threadIdx.x, lane = tid & 63, wid = tid >> 6;
    const int quad = lane >> 4, l15 = lane & 15;
    // XCD-affine swizzle: 2048 blocks = 8 xcd x (8 bh x 32 chunks)
    const int lin = blockIdx.x;
    const int slot = lin >> 3;
    const int bh = (lin & 7) + 8 * (slot >> 5);
    const int chunk = slot & 31;
    const int b = bh >> 4;
    const int t0w = chunk * 2 + wid;        // this wave's q-tile index
    const int l0 = t0w * 16;

    const __bf16* Qbase = Qh + (size_t)bh * 65536;
    const __bf16* Kbase = Kh + (size_t)bh * 65536;
    const __bf16* Vbase = Vt + (size_t)bh * 65536;
    const int* maskb = mask + b * 1024;
    const __bf16* rlo = relkp + 17408;

    // static per-lane staging offsets (4 chunks per lane; wave0=K, wave1=V)
    int gK[4], lK[4], gV[4], lV[4];
    #pragma unroll
    for (int ii = 0; ii < 4; ++ii) {
        const int ch = ii * 64 + lane;          // 0..255
        {   // K: chunk ch -> row r pos p holds global chunk g = p ^ (r&7)
            const int r = ch >> 3, p = ch & 7, g = p ^ (r & 7);
            gK[ii] = r * 64 + g * 8;
            lK[ii] = ch * 8;
        }
        {   // V: chunk ch -> d-row, pos p holds g = p ^ ((d>>1)&3)
            const int d = ch >> 2, p = ch & 3, g = p ^ ((d >> 1) & 3);
            gV[ii] = d * 32 + g * 8;
            lV[ii] = ch * 8;
        }
    }

    // stage pc=0 into buffer 0 (latency hidden under the prologue below)
    if (wid == 0) {
        #pragma unroll
        for (int ii = 0; ii < 4; ++ii)
            async16(Kbase + gK[ii], &Ks[0][0] + lK[ii]);
    } else {
        #pragma unroll
        for (int ii = 0; ii < 4; ++ii)
            async16(Vbase + gV[ii], &Vs[0][0] + lV[ii]);
    }

    const bf16x8_t aq0 = *(const bf16x8_t*)(Qbase + (l0 + l15) * 64 + quad * 8);
    const bf16x8_t aq1 = *(const bf16x8_t*)(Qbase + (l0 + l15) * 64 + 32 + quad * 8);

    // c0/c1 via MFMA: B cols 0/1 hold relk rows 0/256 (hi+lo) -> shfl bcast.
    float c0[4], c1[4];
    {
        const int jr = (l15 == 1) ? 256 : 0;
        const bf16x8_t bh0 = *(const bf16x8_t*)(relkp + jr * 64 + quad * 8);
        const bf16x8_t bh1 = *(const bf16x8_t*)(relkp + jr * 64 + 32 + quad * 8);
        const bf16x8_t bl0 = *(const bf16x8_t*)(rlo + jr * 64 + quad * 8);
        const bf16x8_t bl1 = *(const bf16x8_t*)(rlo + jr * 64 + 32 + quad * 8);
        f32x4_t cr = (f32x4_t){0.f, 0.f, 0.f, 0.f};
        cr = MFMA16(aq0, bl0, cr);
        cr = MFMA16(aq1, bl1, cr);
        cr = MFMA16(aq0, bh0, cr);
        cr = MFMA16(aq1, bh1, cr);
        #pragma unroll
        for (int v = 0; v < 4; ++v) {
            c0[v] = __shfl(cr[v], (lane & 48), 64);
            c1[v] = __shfl(cr[v], (lane & 48) | 1, 64);
        }
    }

    {   // zero own w_s (544 uint4 per wave)
        uint4* wz = (uint4*)&w_s[wid][0][0];
        for (int t = lane; t < 544; t += 64) wz[t] = (uint4){0u, 0u, 0u, 0u};
    }

    f32x4_t o[4];
    #pragma unroll
    for (int dt = 0; dt < 4; ++dt) o[dt] = (f32x4_t){0.f, 0.f, 0.f, 0.f};
    float rowsum[4] = {0.f, 0.f, 0.f, 0.f};
    float e0[4] = {0.f, 0.f, 0.f, 0.f};
    float e1[4] = {0.f, 0.f, 0.f, 0.f};

    __syncthreads();   // pc=0 staged (barrier drains vmcnt), w_s zeroed

    for (int pc = 0; pc < 32; ++pc) {
        const int cur = pc & 1;
        // issue next pair's staging BEFORE computing this one (dbuf pipeline)
        if (pc + 1 < 32) {
            if (wid == 0) {
                #pragma unroll
                for (int ii = 0; ii < 4; ++ii)
                    async16(Kbase + (pc + 1) * 2048 + gK[ii], &Ks[cur ^ 1][0] + lK[ii]);
            } else {
                #pragma unroll
                for (int ii = 0; ii < 4; ++ii)
                    async16(Vbase + (pc + 1) * 2048 + gV[ii], &Vs[cur ^ 1][0] + lV[ii]);
            }
        }

        const int rb0 = pc * 32;
        const int tI0 = pc * 2;
        #pragma unroll
        for (int sl = 0; sl < 2; ++sl) {
            const int tI = tI0 + sl;
            const int dist = tI - t0w;
            const int R = sl * 16 + l15;
            const bf16x8_t kb0 =
                *(const bf16x8_t*)(&Ks[cur][0] + R * 64 + (quad ^ (R & 7)) * 8);
            const bf16x8_t kb1 =
                *(const bf16x8_t*)(&Ks[cur][0] + R * 64 + (((quad + 4) ^ (R & 7))) * 8);
            f32x4_t s = (f32x4_t){0.f, 0.f, 0.f, 0.f};
            s = MFMA16(aq0, kb0, s);
            s = MFMA16(aq1, kb1, s);
            const float madd = (maskb[rb0 + R] == 0) ? -1.0e9f : 0.f;

            if (dist <= -9 || dist >= 9) {      // FAR tile: fully clipped bias
                const bool isLo = dist < 0;
                #pragma unroll
                for (int v = 0; v < 4; ++v) {
                    const float cc = isLo ? c0[v] : c1[v];
                    const float p = __expf(fmaf(s[v], SCALE, cc) + madd);
                    const __bf16 pb = (__bf16)p;
                    const float pf = (float)pb;
                    rowsum[v] += pf;
                    if (isLo) e0[v] += pf; else e1[v] += pf;
                    p_s[wid][quad * 4 + v][sl * 16 + l15] = pb;
                }
            } else {                            // BAND tile: on-the-fly bias
                const int base = dist * 16 + 128;          // 0..256
                // qb[row][c] = Q[row]·relk[base-15+c], c=0..31 (hi+lo)
                int ra = base - 15 + l15;                  // -15..271
                ra = ra < 0 ? 0 : (ra > 256 ? 256 : ra);
                int rb2 = base + 1 + l15;                  // 1..272
                rb2 = rb2 > 256 ? 256 : rb2;
                const bf16x8_t hA0 = *(const bf16x8_t*)(relkp + ra * 64 + quad * 8);
                const bf16x8_t hA1 = *(const bf16x8_t*)(relkp + ra * 64 + 32 + quad * 8);
                const bf16x8_t lA0 = *(const bf16x8_t*)(rlo + ra * 64 + quad * 8);
                const bf16x8_t lA1 = *(const bf16x8_t*)(rlo + ra * 64 + 32 + quad * 8);
                const bf16x8_t hB0 = *(const bf16x8_t*)(relkp + rb2 * 64 + quad * 8);
                const bf16x8_t hB1 = *(const bf16x8_t*)(relkp + rb2 * 64 + 32 + quad * 8);
                const bf16x8_t lB0 = *(const bf16x8_t*)(rlo + rb2 * 64 + quad * 8);
                const bf16x8_t lB1 = *(const bf16x8_t*)(rlo + rb2 * 64 + 32 + quad * 8);
                f32x4_t qbA = (f32x4_t){0.f, 0.f, 0.f, 0.f};
                f32x4_t qbB = (f32x4_t){0.f, 0.f, 0.f, 0.f};
                qbA = MFMA16(aq0, lA0, qbA);
                qbA = MFMA16(aq1, lA1, qbA);
                qbA = MFMA16(aq0, hA0, qbA);
                qbA = MFMA16(aq1, hA1, qbA);
                qbB = MFMA16(aq0, lB0, qbB);
                qbB = MFMA16(aq1, lB1, qbB);
                qbB = MFMA16(aq0, hB0, qbB);
                qbB = MFMA16(aq1, hB1, qbB);
                #pragma unroll
                for (int v = 0; v < 4; ++v) {
                    const int lrow = quad * 4 + v;
                    const int c = l15 + 15 - lrow;          // 0..30
                    const int src = (lane & 48) | (c & 15);
                    const float bA = __shfl(qbA[v], src, 64);
                    const float bB = __shfl(qbB[v], src, 64);
                    const float qbv = (c & 16) ? bB : bA;
                    const int j = base + l15 - lrow;        // -15..271
                    const float bias = (j < 0) ? c0[v] : ((j > 256) ? c1[v] : qbv);
                    const float p = __expf(fmaf(s[v], SCALE, bias) + madd);
                    const __bf16 pb = (__bf16)p;
                    const float pf = (float)pb;
                    rowsum[v] += pf;
                    p_s[wid][lrow][sl * 16 + l15] = pb;
                    if (j <= 0)        e0[v] += pf;
                    else if (j >= 256) e1[v] += pf;
                    else               w_s[wid][lrow][j] = pb;
                }
            }
        }
        // PV over the 32-row pair
        const bf16x8_t pa = *(const bf16x8_t*)(&p_s[wid][l15][quad * 8]);
        #pragma unroll
        for (int dt = 0; dt < 4; ++dt) {
            const int D = dt * 16 + l15;
            const bf16x8_t vb =
                *(const bf16x8_t*)(&Vs[cur][0] + D * 32 + ((quad ^ ((D >> 1) & 3))) * 8);
            o[dt] = MFMA16(pa, vb, o[dt]);
        }
        __syncthreads();   // drains pc+1 staging (hidden under compute), syncs buffers
    }

    // w @ rel_v over cols 0..255 (col 0 stays zero; e0/e1 applied in epilogue)
    for (int kc = 0; kc < 8; ++kc) {
        const bf16x8_t wa = *(const bf16x8_t*)(&w_s[wid][l15][kc * 32 + quad * 8]);
        #pragma unroll
        for (int dt = 0; dt < 4; ++dt) {
            const bf16x8_t rb =
                *(const bf16x8_t*)(rvT + (dt * 16 + l15) * 288 + kc * 32 + quad * 8);
            o[dt] = MFMA16(wa, rb, o[dt]);
        }
    }

    // reduce scalar partials across the 16 lanes of each quad
    #pragma unroll
    for (int v = 0; v < 4; ++v) {
        #pragma unroll
        for (int mm = 1; mm < 16; mm <<= 1) {
            rowsum[v] += __shfl_xor(rowsum[v], mm, 64);
            e0[v]     += __shfl_xor(e0[v], mm, 64);
            e1[v]     += __shfl_xor(e1[v], mm, 64);
        }
    }

    float rinv[4];
    #pragma unroll
    for (int v = 0; v < 4; ++v)
        rinv[v] = 1.f / rowsum[v];
    const int h = bh & 15;
    #pragma unroll
    for (int dt = 0; dt < 4; ++dt) {
        const int d = dt * 16 + l15;
        const float rv0   = relv[d];
        const float rv256 = relv[256 * 64 + d];
        #pragma unroll
        for (int v = 0; v < 4; ++v) {
            const int lrow = quad * 4 + v;
            const float val = (o[dt][v] + e0[v] * rv0 + e1[v] * rv256) * rinv[v];
            ctx[((size_t)b * 1024 + l0 + lrow) * 1024 + h * 64 + d] = (__bf16)val;
        }
    }
}

// ---------------------------------------------------------------------------
extern "C" void kernel_launch(void* const* d_in, const int* in_sizes, int n_in,
                              void* d_out, int out_size, void* d_ws, size_t ws_size,
                              hipStream_t stream)
{
    const float* q    = (const float*)d_in[0];
    const float* k    = (const float*)d_in[1];
    const float* v    = (const float*)d_in[2];
    const int*   mask = (const int*)  d_in[3];
    const float* wq   = (const float*)d_in[4];
    const float* bq   = (const float*)d_in[5];
    const float* wk   = (const float*)d_in[6];
    const float* bk   = (const float*)d_in[7];
    const float* wv   = (const float*)d_in[8];
    const float* bv   = (const float*)d_in[9];
    const float* wo   = (const float*)d_in[10];
    const float* bo   = (const float*)d_in[11];
    const float* relk = (const float*)d_in[12];
    const float* relv = (const float*)d_in[13];

    // workspace layout (bf16 elements unless noted); ~70 MB used.
    __bf16* Xbf   = (__bf16*)d_ws;            // 12582912 (q,k,v inputs hi)
    __bf16* Xgap  = Xbf   + 12582912;         // 4194304 (dead pad)
    __bf16* Wqlo  = Xgap  + 4194304;          // 1048576 (wq residual)
    __bf16* Wall  = Wqlo  + 1048576;          // 4194304 (wq,wk,wv,wo hi)
    __bf16* QKVh  = Wall  + 4194304;          // 12582912 (Q, K, V pair-tiled)
    __bf16* ctx   = QKVh  + 12582912;         // 4194304
    __bf16* relkp = ctx   + 4194304;          // 34816 (hi | lo)
    __bf16* rvT   = relkp + 34816;            // 18432

    cast_all_kernel<<<16419, 256, 0, stream>>>(q, k, v, wq, wk, wv, wo, relk, relv,
                                               Xbf, Wall, relkp, rvT, Wqlo);
    gemm_qkv_kernel<<<dim3(8, 32, 3), 256, 0, stream>>>(Xbf, Wall, Wqlo,
                                                        bq, bk, bv, QKVh);
    attn_fused_kernel<<<2048, 128, 0, stream>>>(QKVh, QKVh + 4194304,
                                                QKVh + 2 * 4194304, relkp,
                                                rvT, mask, relv, ctx);
    gemm_out_kernel<<<dim3(8, 32, 1), 256, 0, stream>>>(ctx, Wall + 3 * 1048576,
                                                        bo, (float*)d_out);
}

// Round 5
// 305.777 us; speedup vs baseline: 1.1144x; 1.1144x over previous
//
#include <hip/hip_runtime.h>
#include <hip/hip_bf16.h>

// Problem constants
#define S_LEN  1024
#define DMODEL 1024
#define NHEADS 16
#define DK     64
#define SCALE  0.125f
// rel table: 257 rows (padded); rvT pitch 288.
// V layout (global): pair-tiled [bh][r/32][d][r%32] -> each 32-k V tile is a
// contiguous 4KB block, enabling coalesced global_load_lds staging.
// attn_fused (R5): 1024 blocks x 256 thr (4 waves, 64 q-rows; wave owns one
// 16-row q-tile). K/V staged through a DEPTH-3 LDS ring via global_load_lds;
// per iteration: s_waitcnt vmcnt(2) [own stage pc landed] -> raw s_barrier
// [cross-wave visibility] -> issue stage pc+2 -> compute pc. Loads stay in
// flight ACROSS barriers (counted vmcnt, never 0 in-loop) - kills the
// vmcnt(0)-drain stall that made R4's dbuf a no-op. Band bias on the fly
// (Q @ rel_k window); the upper bias block of slot d is the lower block of
// slot d+1 -> register carry halves bias MFMAs (8->4/slot). rel_v via
// per-wave w_s histogram (pitch 264) + 8-chunk GEMM; e0/e1 rank-1 edges.

typedef __bf16 bf16x8_t __attribute__((ext_vector_type(8)));
typedef __bf16 bf16x4_t __attribute__((ext_vector_type(4)));
typedef float  f32x4_t  __attribute__((ext_vector_type(4)));

#define MFMA16(A, B, C) __builtin_amdgcn_mfma_f32_16x16x32_bf16((A), (B), (C), 0, 0, 0)

__device__ __forceinline__ void async16(const void* g, void* l) {
    __builtin_amdgcn_global_load_lds(
        (const __attribute__((address_space(1))) unsigned int*)g,
        (__attribute__((address_space(3))) unsigned int*)l, 16, 0, 0);
}

// ---------------------------------------------------------------------------
// Kernel 1: cast inputs to bf16 + build padded rel tables.
__global__ __launch_bounds__(256) void cast_all_kernel(
    const float* __restrict__ q, const float* __restrict__ k, const float* __restrict__ v,
    const float* __restrict__ wq, const float* __restrict__ wk,
    const float* __restrict__ wv, const float* __restrict__ wo,
    const float* __restrict__ relk, const float* __restrict__ relv,
    __bf16* __restrict__ Xbf, __bf16* __restrict__ Wall,
    __bf16* __restrict__ relkp, __bf16* __restrict__ rvT,
    __bf16* __restrict__ Wqlo)
{
    const long i = (long)blockIdx.x * 256 + threadIdx.x;   // vec4 index
    if (i < 3145728) {                       // X region
        const int z   = (int)(i >> 20);
        const long rem = i & 1048575;
        const float4 s = ((const float4*)(z == 0 ? q : (z == 1 ? k : v)))[rem];
        bf16x4_t h;
        h[0] = (__bf16)s.x; h[1] = (__bf16)s.y; h[2] = (__bf16)s.z; h[3] = (__bf16)s.w;
        *(bf16x4_t*)(Xbf + ((size_t)z << 22) + rem * 4) = h;
    } else if (i < 3145728 + 1048576) {      // W region
        const long wi = i - 3145728;
        const int z   = (int)(wi >> 18);
        const long rem = wi & 262143;
        const float* src = (z == 0) ? wq : (z == 1) ? wk : (z == 2) ? wv : wo;
        const float4 s = ((const float4*)src)[rem];
        const float xs[4] = {s.x, s.y, s.z, s.w};
        bf16x4_t h;
        #pragma unroll
        for (int t = 0; t < 4; ++t) h[t] = (__bf16)xs[t];
        *(bf16x4_t*)(Wall + ((size_t)z << 20) + rem * 4) = h;
        if (z == 0) {
            bf16x4_t l;
            #pragma unroll
            for (int t = 0; t < 4; ++t) l[t] = (__bf16)(xs[t] - (float)h[t]);
            *(bf16x4_t*)(Wqlo + rem * 4) = l;
        }
    } else if (i < 3145728 + 1048576 + 4352) {   // relk hi+lo (272 rows x 64)
        const long ri = i - (3145728 + 1048576);
        const int j  = (int)(ri >> 4);
        const int d4 = (int)(ri & 15) * 4;
        bf16x4_t h, l;
        if (j < 257) {
            const float4 s = *(const float4*)(relk + j * 64 + d4);
            const float xs[4] = {s.x, s.y, s.z, s.w};
            #pragma unroll
            for (int t = 0; t < 4; ++t) {
                h[t] = (__bf16)xs[t];
                l[t] = (__bf16)(xs[t] - (float)h[t]);
            }
        } else {
            #pragma unroll
            for (int t = 0; t < 4; ++t) { h[t] = (__bf16)0.f; l[t] = (__bf16)0.f; }
        }
        *(bf16x4_t*)(relkp + j * 64 + d4) = h;
        *(bf16x4_t*)(relkp + 17408 + j * 64 + d4) = l;
    } else if (i < 3145728 + 1048576 + 4352 + 4608) { // rvT: [64][288], rvT[d][j]=rel_v[j][d]
        const long ri = i - (3145728 + 1048576 + 4352);
        const int d  = (int)(ri / 72);
        const int j4 = (int)(ri % 72) * 4;
        bf16x4_t o;
        #pragma unroll
        for (int t = 0; t < 4; ++t) {
            const int j = j4 + t;
            o[t] = (j < 257) ? (__bf16)relv[j * 64 + d] : (__bf16)0.f;
        }
        *(bf16x4_t*)(rvT + d * 288 + j4) = o;
    }
}

// ---------------------------------------------------------------------------
// Shared 128x128 tile GEMM core: acc += A(128xK) @ W(128xK)^T, K=1024, BK=32.
__device__ __forceinline__ void gemm128_core(
    const __bf16* __restrict__ A, const __bf16* __restrict__ W,
    __bf16* As, __bf16* Ws, f32x4_t acc[4][4])
{
    const int tid  = threadIdx.x;
    const int lane = tid & 63;
    const int quad = lane >> 4;
    const int l15  = lane & 15;
    const int wid  = tid >> 6;
    const int wm = wid >> 1, wn = wid & 1;

    for (int kt = 0; kt < 32; ++kt) {
        #pragma unroll
        for (int r = 0; r < 2; ++r) {
            const int c = r * 256 + tid;        // 512 chunks of 16B per tile
            const int row = c >> 2, kb = c & 3;
            async16(A + row * 1024 + kt * 32 + kb * 8, As + c * 8);
            async16(W + row * 1024 + kt * 32 + kb * 8, Ws + c * 8);
        }
        __syncthreads();
        bf16x8_t af[4], wf[4];
        #pragma unroll
        for (int i = 0; i < 4; ++i) {
            af[i] = *(const bf16x8_t*)(As + (wm * 64 + i * 16 + l15) * 32 + quad * 8);
            wf[i] = *(const bf16x8_t*)(Ws + (wn * 64 + i * 16 + l15) * 32 + quad * 8);
        }
        #pragma unroll
        for (int i = 0; i < 4; ++i)
            #pragma unroll
            for (int j = 0; j < 4; ++j)
                acc[i][j] = MFMA16(af[i], wf[j], acc[i][j]);
        __syncthreads();
    }
}

// ---------------------------------------------------------------------------
// Kernel 2: QKV projections. z=0:Q (W hi+lo), z=1:K [bh][s][d];
// z=2:V pair-tiled [bh][s/32][d][s%32].
__global__ __launch_bounds__(256) void gemm_qkv_kernel(
    const __bf16* __restrict__ Xbf, const __bf16* __restrict__ Wall,
    const __bf16* __restrict__ Wqlo,
    const float* __restrict__ bq, const float* __restrict__ bk, const float* __restrict__ bv,
    __bf16* __restrict__ QKVh)
{
    __shared__ __bf16 As[4096], Ws[4096];
    const int z = blockIdx.z;
    const __bf16* A = Xbf + (size_t)z * 4194304 + (size_t)blockIdx.y * 131072;
    const __bf16* W = Wall + (size_t)z * 1048576 + (size_t)blockIdx.x * 131072;
    f32x4_t acc[4][4];
    #pragma unroll
    for (int i = 0; i < 4; ++i)
        #pragma unroll
        for (int j = 0; j < 4; ++j)
            acc[i][j] = (f32x4_t){0.f, 0.f, 0.f, 0.f};

    gemm128_core(A, W, As, Ws, acc);
    if (z == 0)   // Q = Xhi*(Whi+Wlo)
        gemm128_core(A, Wqlo + (size_t)blockIdx.x * 131072, As, Ws, acc);

    const int tid = threadIdx.x, lane = tid & 63, quad = lane >> 4, l15 = lane & 15;
    const int wid = tid >> 6, wm = wid >> 1, wn = wid & 1;
    const int m0 = blockIdx.y * 128 + wm * 64;
    const int n0 = blockIdx.x * 128 + wn * 64;
    const float* bias = (z == 0) ? bq : ((z == 1) ? bk : bv);
    __bf16* dst = QKVh + (size_t)z * 4194304;

    if (z < 2) {
        #pragma unroll
        for (int j = 0; j < 4; ++j) {
            const int n = n0 + j * 16 + l15;
            const float bn = bias[n];
            #pragma unroll
            for (int i = 0; i < 4; ++i) {
                #pragma unroll
                for (int v = 0; v < 4; ++v) {
                    const int m = m0 + i * 16 + quad * 4 + v;
                    dst[((((m >> 10) * 16 + (n >> 6)) << 16)) + ((m & 1023) << 6) + (n & 63)]
                        = (__bf16)(acc[i][j][v] + bn);
                }
            }
        }
    } else {
        #pragma unroll
        for (int j = 0; j < 4; ++j) {
            const int n = n0 + j * 16 + l15;
            const float bn = bias[n];
            #pragma unroll
            for (int i = 0; i < 4; ++i) {
                const int m = m0 + i * 16 + quad * 4;
                bf16x4_t pk;
                #pragma unroll
                for (int v = 0; v < 4; ++v) pk[v] = (__bf16)(acc[i][j][v] + bn);
                const int s = m & 1023, d = n & 63;
                const size_t idx = (((size_t)((m >> 10) * 16 + (n >> 6))) << 16)
                                 + (size_t)(s >> 5) * 2048 + d * 32 + (s & 31);
                *(bf16x4_t*)(dst + idx) = pk;
            }
        }
    }
}

// ---------------------------------------------------------------------------
// Kernel 5: output projection, fp32 epilogue straight to d_out.
__global__ __launch_bounds__(256) void gemm_out_kernel(
    const __bf16* __restrict__ ctx, const __bf16* __restrict__ Wo,
    const float* __restrict__ bo, float* __restrict__ out)
{
    __shared__ __bf16 As[4096], Ws[4096];
    const __bf16* A = ctx + (size_t)blockIdx.y * 131072;
    const __bf16* W = Wo + (size_t)blockIdx.x * 131072;
    f32x4_t acc[4][4];
    #pragma unroll
    for (int i = 0; i < 4; ++i)
        #pragma unroll
        for (int j = 0; j < 4; ++j)
            acc[i][j] = (f32x4_t){0.f, 0.f, 0.f, 0.f};
    gemm128_core(A, W, As, Ws, acc);

    const int tid = threadIdx.x, lane = tid & 63, quad = lane >> 4, l15 = lane & 15;
    const int wid = tid >> 6, wm = wid >> 1, wn = wid & 1;
    const int m0 = blockIdx.y * 128 + wm * 64;
    const int n0 = blockIdx.x * 128 + wn * 64;
    #pragma unroll
    for (int j = 0; j < 4; ++j) {
        const int n = n0 + j * 16 + l15;
        const float bn = bo[n];
        #pragma unroll
        for (int i = 0; i < 4; ++i)
            #pragma unroll
            for (int v = 0; v < 4; ++v) {
                const int m = m0 + i * 16 + quad * 4 + v;
                out[(size_t)m * 1024 + n] = acc[i][j][v] + bn;
            }
    }
}

// ---------------------------------------------------------------------------
// Kernel 3: FUSED attention, 4-wave / depth-3 ring / counted vmcnt (header).
__global__ __launch_bounds__(256, 2) void attn_fused_kernel(
    const __bf16* __restrict__ Qh, const __bf16* __restrict__ Kh,
    const __bf16* __restrict__ Vt, const __bf16* __restrict__ relkp,
    const __bf16* __restrict__ rvT, const int* __restrict__ mask,
    const float* __restrict__ relv, __bf16* __restrict__ ctx)
{
    __shared__ __align__(16) __bf16 Ks[3][2048];     // ring: 32r x 64d, swizzled
    __shared__ __align__(16) __bf16 Vs[3][2048];     // ring: 64d x 32r, swizzled
    __shared__ __align__(16) __bf16 p_s[4][16][40];  // per-wave P staging
    __shared__ __align__(16) __bf16 w_s[4][16][264]; // per-wave rel_v histogram

    const int tid = threadIdx.x, lane = tid & 63, wid = tid >> 6;
    const int quad = lane >> 4, l15 = lane & 15;
    // XCD-affine swizzle: 1024 blocks = 8 xcd x (8 bh x 16 chunks)
    const int lin = blockIdx.x;
    const int slot = lin >> 3;
    const int bh = (lin & 7) + 8 * (slot >> 4);
    const int chunk = slot & 15;
    const int b = bh >> 4;
    const int t0w = chunk * 4 + wid;        // this wave's q-tile index
    const int l0 = t0w * 16;

    const __bf16* Qbase = Qh + (size_t)bh * 65536;
    const __bf16* Kbase = Kh + (size_t)bh * 65536;
    const __bf16* Vbase = Vt + (size_t)bh * 65536;
    const int* maskb = mask + b * 1024;
    const __bf16* rlo = relkp + 17408;

    // staging offsets: waves 0,1 stage K (2 x 1KB each), waves 2,3 stage V.
    int gKo[2], lKo[2], gVo[2], lVo[2];
    #pragma unroll
    for (int ii = 0; ii < 2; ++ii) {
        const int chK = (wid & 1) * 128 + ii * 64 + lane;   // 0..255
        const int rK = chK >> 3, pK = chK & 7, gK = pK ^ (rK & 7);
        gKo[ii] = rK * 64 + gK * 8;
        lKo[ii] = chK * 8;
        const int chV = (wid & 1) * 128 + ii * 64 + lane;
        const int dV = chV >> 2, pV = chV & 3, gV = pV ^ ((dV >> 1) & 3);
        gVo[ii] = dV * 32 + gV * 8;
        lVo[ii] = chV * 8;
    }

    #define STAGE(t, buf)                                                     \
        do {                                                                  \
            if (wid < 2) {                                                    \
                async16(Kbase + (t) * 2048 + gKo[0], &Ks[buf][0] + lKo[0]);   \
                async16(Kbase + (t) * 2048 + gKo[1], &Ks[buf][0] + lKo[1]);   \
            } else {                                                          \
                async16(Vbase + (t) * 2048 + gVo[0], &Vs[buf][0] + lVo[0]);   \
                async16(Vbase + (t) * 2048 + gVo[1], &Vs[buf][0] + lVo[1]);   \
            }                                                                 \
        } while (0)

    // prologue: stage pairs 0 and 1 (retired by the compiler's waits for the
    // c0/c1 relkp loads below, so the loop's vmcnt ledger starts clean).
    STAGE(0, 0);
    STAGE(1, 1);

    const bf16x8_t aq0 = *(const bf16x8_t*)(Qbase + (l0 + l15) * 64 + quad * 8);
    const bf16x8_t aq1 = *(const bf16x8_t*)(Qbase + (l0 + l15) * 64 + 32 + quad * 8);

    // c0/c1 via MFMA: B cols 0/1 hold relk rows 0/256 (hi+lo) -> shfl bcast.
    float c0[4], c1[4];
    {
        const int jr = (l15 == 1) ? 256 : 0;
        const bf16x8_t bh0 = *(const bf16x8_t*)(relkp + jr * 64 + quad * 8);
        const bf16x8_t bh1 = *(const bf16x8_t*)(relkp + jr * 64 + 32 + quad * 8);
        const bf16x8_t bl0 = *(const bf16x8_t*)(rlo + jr * 64 + quad * 8);
        const bf16x8_t bl1 = *(const bf16x8_t*)(rlo + jr * 64 + 32 + quad * 8);
        f32x4_t cr = (f32x4_t){0.f, 0.f, 0.f, 0.f};
        cr = MFMA16(aq0, bl0, cr);
        cr = MFMA16(aq1, bl1, cr);
        cr = MFMA16(aq0, bh0, cr);
        cr = MFMA16(aq1, bh1, cr);
        #pragma unroll
        for (int v = 0; v < 4; ++v) {
            c0[v] = __shfl(cr[v], (lane & 48), 64);
            c1[v] = __shfl(cr[v], (lane & 48) | 1, 64);
        }
    }

    {   // zero own w_s (528 uint4 per wave; per-wave, no barrier needed)
        uint4* wz = (uint4*)&w_s[wid][0][0];
        for (int t = lane; t < 528; t += 64) wz[t] = (uint4){0u, 0u, 0u, 0u};
    }

    f32x4_t o[4];
    #pragma unroll
    for (int dt = 0; dt < 4; ++dt) o[dt] = (f32x4_t){0.f, 0.f, 0.f, 0.f};
    float rowsum[4] = {0.f, 0.f, 0.f, 0.f};
    float e0[4] = {0.f, 0.f, 0.f, 0.f};
    float e1[4] = {0.f, 0.f, 0.f, 0.f};
    f32x4_t qb_carry = (f32x4_t){0.f, 0.f, 0.f, 0.f};

    for (int pc = 0; pc < 32; ++pc) {
        // own stage pc landed (2 newer ops = stage pc+1); last iter: drain.
        if (pc < 31) asm volatile("s_waitcnt vmcnt(2)" ::: "memory");
        else         asm volatile("s_waitcnt vmcnt(0)" ::: "memory");
        asm volatile("" ::: "memory");
        __builtin_amdgcn_s_barrier();       // cross-wave: K and V of pc visible
        asm volatile("" ::: "memory");
        if (pc + 2 < 32) STAGE(pc + 2, (pc + 2) % 3);   // overwrites buf of pc-1

        const int cur = pc % 3;
        const int rb0 = pc * 32;
        const int tI0 = pc * 2;
        #pragma unroll
        for (int sl = 0; sl < 2; ++sl) {
            const int tI = tI0 + sl;
            const int dist = tI - t0w;
            const int R = sl * 16 + l15;
            const bf16x8_t kb0 =
                *(const bf16x8_t*)(&Ks[cur][0] + R * 64 + (quad ^ (R & 7)) * 8);
            const bf16x8_t kb1 =
                *(const bf16x8_t*)(&Ks[cur][0] + R * 64 + (((quad + 4) ^ (R & 7))) * 8);
            f32x4_t s = (f32x4_t){0.f, 0.f, 0.f, 0.f};
            s = MFMA16(aq0, kb0, s);
            s = MFMA16(aq1, kb1, s);
            const float madd = (maskb[rb0 + R] == 0) ? -1.0e9f : 0.f;

            if (dist <= -9 || dist >= 9) {      // FAR tile: fully clipped bias
                const bool isLo = dist < 0;
                #pragma unroll
                for (int v = 0; v < 4; ++v) {
                    const float cc = isLo ? c0[v] : c1[v];
                    const float p = __expf(fmaf(s[v], SCALE, cc) + madd);
                    const __bf16 pb = (__bf16)p;
                    const float pf = (float)pb;
                    rowsum[v] += pf;
                    if (isLo) e0[v] += pf; else e1[v] += pf;
                    p_s[wid][quad * 4 + v][sl * 16 + l15] = pb;
                }
            } else {                            // BAND tile: on-the-fly bias
                const int base = dist * 16 + 128;          // 0..256
                // qbA: cols base-15..base (carried from prev slot's qbB when
                // the previous slot was also band); qbB: cols base+1..base+16.
                f32x4_t qbA;
                const bool seed = (dist == -8) || (tI == 0);
                if (seed) {
                    int ra = base - 15 + l15;              // -15..271
                    ra = ra < 0 ? 0 : (ra > 256 ? 256 : ra);
                    const bf16x8_t hA0 = *(const bf16x8_t*)(relkp + ra * 64 + quad * 8);
                    const bf16x8_t hA1 = *(const bf16x8_t*)(relkp + ra * 64 + 32 + quad * 8);
                    const bf16x8_t lA0 = *(const bf16x8_t*)(rlo + ra * 64 + quad * 8);
                    const bf16x8_t lA1 = *(const bf16x8_t*)(rlo + ra * 64 + 32 + quad * 8);
                    qbA = (f32x4_t){0.f, 0.f, 0.f, 0.f};
                    qbA = MFMA16(aq0, lA0, qbA);
                    qbA = MFMA16(aq1, lA1, qbA);
                    qbA = MFMA16(aq0, hA0, qbA);
                    qbA = MFMA16(aq1, hA1, qbA);
                } else {
                    qbA = qb_carry;
                }
                int rb2 = base + 1 + l15;                  // 1..272
                rb2 = rb2 > 256 ? 256 : rb2;
                const bf16x8_t hB0 = *(const bf16x8_t*)(relkp + rb2 * 64 + quad * 8);
                const bf16x8_t hB1 = *(const bf16x8_t*)(relkp + rb2 * 64 + 32 + quad * 8);
                const bf16x8_t lB0 = *(const bf16x8_t*)(rlo + rb2 * 64 + quad * 8);
                const bf16x8_t lB1 = *(const bf16x8_t*)(rlo + rb2 * 64 + 32 + quad * 8);
                f32x4_t qbB = (f32x4_t){0.f, 0.f, 0.f, 0.f};
                qbB = MFMA16(aq0, lB0, qbB);
                qbB = MFMA16(aq1, lB1, qbB);
                qbB = MFMA16(aq0, hB0, qbB);
                qbB = MFMA16(aq1, hB1, qbB);
                qb_carry = qbB;
                #pragma unroll
                for (int v = 0; v < 4; ++v) {
                    const int lrow = quad * 4 + v;
                    const int c = l15 + 15 - lrow;          // 0..30
                    const int src = (lane & 48) | (c & 15);
                    const float bA = __shfl(qbA[v], src, 64);
                    const float bB = __shfl(qbB[v], src, 64);
                    const float qbv = (c & 16) ? bB : bA;
                    const int j = base + l15 - lrow;        // -15..271
                    const float bias = (j < 0) ? c0[v] : ((j > 256) ? c1[v] : qbv);
                    const float p = __expf(fmaf(s[v], SCALE, bias) + madd);
                    const __bf16 pb = (__bf16)p;
                    const float pf = (float)pb;
                    rowsum[v] += pf;
                    p_s[wid][lrow][sl * 16 + l15] = pb;
                    if (j <= 0)        e0[v] += pf;
                    else if (j >= 256) e1[v] += pf;
                    else               w_s[wid][lrow][j] = pb;
                }
            }
        }
        // PV over the 32-row pair
        const bf16x8_t pa = *(const bf16x8_t*)(&p_s[wid][l15][quad * 8]);
        #pragma unroll
        for (int dt = 0; dt < 4; ++dt) {
            const int D = dt * 16 + l15;
            const bf16x8_t vb =
                *(const bf16x8_t*)(&Vs[cur][0] + D * 32 + ((quad ^ ((D >> 1) & 3))) * 8);
            o[dt] = MFMA16(pa, vb, o[dt]);
        }
    }
    #undef STAGE

    // w @ rel_v over cols 0..255 (col 0 stays zero; e0/e1 applied in epilogue)
    for (int kc = 0; kc < 8; ++kc) {
        const bf16x8_t wa = *(const bf16x8_t*)(&w_s[wid][l15][kc * 32 + quad * 8]);
        #pragma unroll
        for (int dt = 0; dt < 4; ++dt) {
            const bf16x8_t rb =
                *(const bf16x8_t*)(rvT + (dt * 16 + l15) * 288 + kc * 32 + quad * 8);
            o[dt] = MFMA16(wa, rb, o[dt]);
        }
    }

    // reduce scalar partials across the 16 lanes of each quad
    #pragma unroll
    for (int v = 0; v < 4; ++v) {
        #pragma unroll
        for (int mm = 1; mm < 16; mm <<= 1) {
            rowsum[v] += __shfl_xor(rowsum[v], mm, 64);
            e0[v]     += __shfl_xor(e0[v], mm, 64);
            e1[v]     += __shfl_xor(e1[v], mm, 64);
        }
    }

    float rinv[4];
    #pragma unroll
    for (int v = 0; v < 4; ++v)
        rinv[v] = 1.f / rowsum[v];
    const int h = bh & 15;
    #pragma unroll
    for (int dt = 0; dt < 4; ++dt) {
        const int d = dt * 16 + l15;
        const float rv0   = relv[d];
        const float rv256 = relv[256 * 64 + d];
        #pragma unroll
        for (int v = 0; v < 4; ++v) {
            const int lrow = quad * 4 + v;
            const float val = (o[dt][v] + e0[v] * rv0 + e1[v] * rv256) * rinv[v];
            ctx[((size_t)b * 1024 + l0 + lrow) * 1024 + h * 64 + d] = (__bf16)val;
        }
    }
}

// ---------------------------------------------------------------------------
extern "C" void kernel_launch(void* const* d_in, const int* in_sizes, int n_in,
                              void* d_out, int out_size, void* d_ws, size_t ws_size,
                              hipStream_t stream)
{
    const float* q    = (const float*)d_in[0];
    const float* k    = (const float*)d_in[1];
    const float* v    = (const float*)d_in[2];
    const int*   mask = (const int*)  d_in[3];
    const float* wq   = (const float*)d_in[4];
    const float* bq   = (const float*)d_in[5];
    const float* wk   = (const float*)d_in[6];
    const float* bk   = (const float*)d_in[7];
    const float* wv   = (const float*)d_in[8];
    const float* bv   = (const float*)d_in[9];
    const float* wo   = (const float*)d_in[10];
    const float* bo   = (const float*)d_in[11];
    const float* relk = (const float*)d_in[12];
    const float* relv = (const float*)d_in[13];

    // workspace layout (bf16 elements unless noted); ~70 MB used.
    __bf16* Xbf   = (__bf16*)d_ws;            // 12582912 (q,k,v inputs hi)
    __bf16* Xgap  = Xbf   + 12582912;         // 4194304 (dead pad)
    __bf16* Wqlo  = Xgap  + 4194304;          // 1048576 (wq residual)
    __bf16* Wall  = Wqlo  + 1048576;          // 4194304 (wq,wk,wv,wo hi)
    __bf16* QKVh  = Wall  + 4194304;          // 12582912 (Q, K, V pair-tiled)
    __bf16* ctx   = QKVh  + 12582912;         // 4194304
    __bf16* relkp = ctx   + 4194304;          // 34816 (hi | lo)
    __bf16* rvT   = relkp + 34816;            // 18432

    cast_all_kernel<<<16419, 256, 0, stream>>>(q, k, v, wq, wk, wv, wo, relk, relv,
                                               Xbf, Wall, relkp, rvT, Wqlo);
    gemm_qkv_kernel<<<dim3(8, 32, 3), 256, 0, stream>>>(Xbf, Wall, Wqlo,
                                                        bq, bk, bv, QKVh);
    attn_fused_kernel<<<1024, 256, 0, stream>>>(QKVh, QKVh + 4194304,
                                                QKVh + 2 * 4194304, relkp,
                                                rvT, mask, relv, ctx);
    gemm_out_kernel<<<dim3(8, 32, 1), 256, 0, stream>>>(ctx, Wall + 3 * 1048576,
                                                        bo, (float*)d_out);
}

// Round 8
// 302.512 us; speedup vs baseline: 1.1264x; 1.0108x over previous
//
#include <hip/hip_runtime.h>
#include <hip/hip_bf16.h>

// Problem constants
#define S_LEN  1024
#define DMODEL 1024
#define NHEADS 16
#define DK     64
#define SCALE  0.125f
// rel table: 257 rows (padded); rvT pitch 288.
// V layout (global): pair-tiled [bh][r/32][d][r%32] -> each 32-k V tile is a
// contiguous 4KB block, enabling coalesced global_load_lds staging.
// attn_fused (R8 = R5 + mask->LDS + setprio): 1024 blocks x 256 thr (4 waves,
// 64 q-rows; wave owns one 16-row q-tile). K/V staged through a DEPTH-3 LDS
// ring via global_load_lds; per iteration: s_waitcnt vmcnt(2) [own stage pc
// landed] -> raw s_barrier [cross-wave visibility] -> issue stage pc+2 ->
// compute pc. R8 changes vs R5 (which passed at 305.8us):
//  (a) mask moved to madd_sb (bf16 LDS, staged in prologue) -- R5's in-loop
//      GLOBAL mask loads were issued after the STAGE ops, and in-order vmcnt
//      retirement meant the compiler's pre-use wait drained the prefetched
//      stages EVERY iteration. Now far-only iterations (~22 of 32 per wave)
//      have a stage-only ledger and the counted vmcnt actually pipelines.
//  (b) s_setprio(1) around the per-iteration compute (T5, +4-7% attn m191).
//  (c) w_s pitch 264->256 so total LDS = 64512 <= 64KB block limit.
// Band bias stays R5's proven on-the-fly path (Q @ rel_k window MFMA with
// register carry + shfl skew resolve); rel_v via per-wave w_s histogram +
// 8-chunk GEMM; e0/e1 rank-1 edges applied in the epilogue.

typedef __bf16 bf16x8_t __attribute__((ext_vector_type(8)));
typedef __bf16 bf16x4_t __attribute__((ext_vector_type(4)));
typedef float  f32x4_t  __attribute__((ext_vector_type(4)));

#define MFMA16(A, B, C) __builtin_amdgcn_mfma_f32_16x16x32_bf16((A), (B), (C), 0, 0, 0)

__device__ __forceinline__ void async16(const void* g, void* l) {
    __builtin_amdgcn_global_load_lds(
        (const __attribute__((address_space(1))) unsigned int*)g,
        (__attribute__((address_space(3))) unsigned int*)l, 16, 0, 0);
}

// ---------------------------------------------------------------------------
// Kernel 1: cast inputs to bf16 + build padded rel tables.
__global__ __launch_bounds__(256) void cast_all_kernel(
    const float* __restrict__ q, const float* __restrict__ k, const float* __restrict__ v,
    const float* __restrict__ wq, const float* __restrict__ wk,
    const float* __restrict__ wv, const float* __restrict__ wo,
    const float* __restrict__ relk, const float* __restrict__ relv,
    __bf16* __restrict__ Xbf, __bf16* __restrict__ Wall,
    __bf16* __restrict__ relkp, __bf16* __restrict__ rvT,
    __bf16* __restrict__ Wqlo)
{
    const long i = (long)blockIdx.x * 256 + threadIdx.x;   // vec4 index
    if (i < 3145728) {                       // X region
        const int z   = (int)(i >> 20);
        const long rem = i & 1048575;
        const float4 s = ((const float4*)(z == 0 ? q : (z == 1 ? k : v)))[rem];
        bf16x4_t h;
        h[0] = (__bf16)s.x; h[1] = (__bf16)s.y; h[2] = (__bf16)s.z; h[3] = (__bf16)s.w;
        *(bf16x4_t*)(Xbf + ((size_t)z << 22) + rem * 4) = h;
    } else if (i < 3145728 + 1048576) {      // W region
        const long wi = i - 3145728;
        const int z   = (int)(wi >> 18);
        const long rem = wi & 262143;
        const float* src = (z == 0) ? wq : (z == 1) ? wk : (z == 2) ? wv : wo;
        const float4 s = ((const float4*)src)[rem];
        const float xs[4] = {s.x, s.y, s.z, s.w};
        bf16x4_t h;
        #pragma unroll
        for (int t = 0; t < 4; ++t) h[t] = (__bf16)xs[t];
        *(bf16x4_t*)(Wall + ((size_t)z << 20) + rem * 4) = h;
        if (z == 0) {
            bf16x4_t l;
            #pragma unroll
            for (int t = 0; t < 4; ++t) l[t] = (__bf16)(xs[t] - (float)h[t]);
            *(bf16x4_t*)(Wqlo + rem * 4) = l;
        }
    } else if (i < 3145728 + 1048576 + 4352) {   // relk hi+lo (272 rows x 64)
        const long ri = i - (3145728 + 1048576);
        const int j  = (int)(ri >> 4);
        const int d4 = (int)(ri & 15) * 4;
        bf16x4_t h, l;
        if (j < 257) {
            const float4 s = *(const float4*)(relk + j * 64 + d4);
            const float xs[4] = {s.x, s.y, s.z, s.w};
            #pragma unroll
            for (int t = 0; t < 4; ++t) {
                h[t] = (__bf16)xs[t];
                l[t] = (__bf16)(xs[t] - (float)h[t]);
            }
        } else {
            #pragma unroll
            for (int t = 0; t < 4; ++t) { h[t] = (__bf16)0.f; l[t] = (__bf16)0.f; }
        }
        *(bf16x4_t*)(relkp + j * 64 + d4) = h;
        *(bf16x4_t*)(relkp + 17408 + j * 64 + d4) = l;
    } else if (i < 3145728 + 1048576 + 4352 + 4608) { // rvT: [64][288], rvT[d][j]=rel_v[j][d]
        const long ri = i - (3145728 + 1048576 + 4352);
        const int d  = (int)(ri / 72);
        const int j4 = (int)(ri % 72) * 4;
        bf16x4_t o;
        #pragma unroll
        for (int t = 0; t < 4; ++t) {
            const int j = j4 + t;
            o[t] = (j < 257) ? (__bf16)relv[j * 64 + d] : (__bf16)0.f;
        }
        *(bf16x4_t*)(rvT + d * 288 + j4) = o;
    }
}

// ---------------------------------------------------------------------------
// Shared 128x128 tile GEMM core: acc += A(128xK) @ W(128xK)^T, K=1024, BK=32.
__device__ __forceinline__ void gemm128_core(
    const __bf16* __restrict__ A, const __bf16* __restrict__ W,
    __bf16* As, __bf16* Ws, f32x4_t acc[4][4])
{
    const int tid  = threadIdx.x;
    const int lane = tid & 63;
    const int quad = lane >> 4;
    const int l15  = lane & 15;
    const int wid  = tid >> 6;
    const int wm = wid >> 1, wn = wid & 1;

    for (int kt = 0; kt < 32; ++kt) {
        #pragma unroll
        for (int r = 0; r < 2; ++r) {
            const int c = r * 256 + tid;        // 512 chunks of 16B per tile
            const int row = c >> 2, kb = c & 3;
            async16(A + row * 1024 + kt * 32 + kb * 8, As + c * 8);
            async16(W + row * 1024 + kt * 32 + kb * 8, Ws + c * 8);
        }
        __syncthreads();
        bf16x8_t af[4], wf[4];
        #pragma unroll
        for (int i = 0; i < 4; ++i) {
            af[i] = *(const bf16x8_t*)(As + (wm * 64 + i * 16 + l15) * 32 + quad * 8);
            wf[i] = *(const bf16x8_t*)(Ws + (wn * 64 + i * 16 + l15) * 32 + quad * 8);
        }
        #pragma unroll
        for (int i = 0; i < 4; ++i)
            #pragma unroll
            for (int j = 0; j < 4; ++j)
                acc[i][j] = MFMA16(af[i], wf[j], acc[i][j]);
        __syncthreads();
    }
}

// ---------------------------------------------------------------------------
// Kernel 2: QKV projections. z=0:Q (W hi+lo), z=1:K [bh][s][d];
// z=2:V pair-tiled [bh][s/32][d][s%32].
__global__ __launch_bounds__(256) void gemm_qkv_kernel(
    const __bf16* __restrict__ Xbf, const __bf16* __restrict__ Wall,
    const __bf16* __restrict__ Wqlo,
    const float* __restrict__ bq, const float* __restrict__ bk, const float* __restrict__ bv,
    __bf16* __restrict__ QKVh)
{
    __shared__ __bf16 As[4096], Ws[4096];
    const int z = blockIdx.z;
    const __bf16* A = Xbf + (size_t)z * 4194304 + (size_t)blockIdx.y * 131072;
    const __bf16* W = Wall + (size_t)z * 1048576 + (size_t)blockIdx.x * 131072;
    f32x4_t acc[4][4];
    #pragma unroll
    for (int i = 0; i < 4; ++i)
        #pragma unroll
        for (int j = 0; j < 4; ++j)
            acc[i][j] = (f32x4_t){0.f, 0.f, 0.f, 0.f};

    gemm128_core(A, W, As, Ws, acc);
    if (z == 0)   // Q = Xhi*(Whi+Wlo)
        gemm128_core(A, Wqlo + (size_t)blockIdx.x * 131072, As, Ws, acc);

    const int tid = threadIdx.x, lane = tid & 63, quad = lane >> 4, l15 = lane & 15;
    const int wid = tid >> 6, wm = wid >> 1, wn = wid & 1;
    const int m0 = blockIdx.y * 128 + wm * 64;
    const int n0 = blockIdx.x * 128 + wn * 64;
    const float* bias = (z == 0) ? bq : ((z == 1) ? bk : bv);
    __bf16* dst = QKVh + (size_t)z * 4194304;

    if (z < 2) {
        #pragma unroll
        for (int j = 0; j < 4; ++j) {
            const int n = n0 + j * 16 + l15;
            const float bn = bias[n];
            #pragma unroll
            for (int i = 0; i < 4; ++i) {
                #pragma unroll
                for (int v = 0; v < 4; ++v) {
                    const int m = m0 + i * 16 + quad * 4 + v;
                    dst[((((m >> 10) * 16 + (n >> 6)) << 16)) + ((m & 1023) << 6) + (n & 63)]
                        = (__bf16)(acc[i][j][v] + bn);
                }
            }
        }
    } else {
        #pragma unroll
        for (int j = 0; j < 4; ++j) {
            const int n = n0 + j * 16 + l15;
            const float bn = bias[n];
            #pragma unroll
            for (int i = 0; i < 4; ++i) {
                const int m = m0 + i * 16 + quad * 4;
                bf16x4_t pk;
                #pragma unroll
                for (int v = 0; v < 4; ++v) pk[v] = (__bf16)(acc[i][j][v] + bn);
                const int s = m & 1023, d = n & 63;
                const size_t idx = (((size_t)((m >> 10) * 16 + (n >> 6))) << 16)
                                 + (size_t)(s >> 5) * 2048 + d * 32 + (s & 31);
                *(bf16x4_t*)(dst + idx) = pk;
            }
        }
    }
}

// ---------------------------------------------------------------------------
// Kernel 5: output projection, fp32 epilogue straight to d_out.
__global__ __launch_bounds__(256) void gemm_out_kernel(
    const __bf16* __restrict__ ctx, const __bf16* __restrict__ Wo,
    const float* __restrict__ bo, float* __restrict__ out)
{
    __shared__ __bf16 As[4096], Ws[4096];
    const __bf16* A = ctx + (size_t)blockIdx.y * 131072;
    const __bf16* W = Wo + (size_t)blockIdx.x * 131072;
    f32x4_t acc[4][4];
    #pragma unroll
    for (int i = 0; i < 4; ++i)
        #pragma unroll
        for (int j = 0; j < 4; ++j)
            acc[i][j] = (f32x4_t){0.f, 0.f, 0.f, 0.f};
    gemm128_core(A, W, As, Ws, acc);

    const int tid = threadIdx.x, lane = tid & 63, quad = lane >> 4, l15 = lane & 15;
    const int wid = tid >> 6, wm = wid >> 1, wn = wid & 1;
    const int m0 = blockIdx.y * 128 + wm * 64;
    const int n0 = blockIdx.x * 128 + wn * 64;
    #pragma unroll
    for (int j = 0; j < 4; ++j) {
        const int n = n0 + j * 16 + l15;
        const float bn = bo[n];
        #pragma unroll
        for (int i = 0; i < 4; ++i)
            #pragma unroll
            for (int v = 0; v < 4; ++v) {
                const int m = m0 + i * 16 + quad * 4 + v;
                out[(size_t)m * 1024 + n] = acc[i][j][v] + bn;
            }
    }
}

// ---------------------------------------------------------------------------
// Kernel 3: FUSED attention, R8 (see header comment).
__global__ __launch_bounds__(256, 2) void attn_fused_kernel(
    const __bf16* __restrict__ Qh, const __bf16* __restrict__ Kh,
    const __bf16* __restrict__ Vt, const __bf16* __restrict__ relkp,
    const __bf16* __restrict__ rvT, const int* __restrict__ mask,
    const float* __restrict__ relv, __bf16* __restrict__ ctx)
{
    __shared__ __align__(16) __bf16 Ks[3][2048];     // ring: 32r x 64d, swizzled
    __shared__ __align__(16) __bf16 Vs[3][2048];     // ring: 64d x 32r, swizzled
    __shared__ __align__(16) __bf16 p_s[4][16][40];  // per-wave P staging
    __shared__ __align__(16) __bf16 w_s[4][16][256]; // per-wave rel_v histogram
    __shared__ __align__(16) __bf16 madd_sb[1024];   // mask -> additive bias (bf16)

    const int tid = threadIdx.x, lane = tid & 63, wid = tid >> 6;
    const int quad = lane >> 4, l15 = lane & 15;
    // XCD-affine swizzle: 1024 blocks = 8 xcd x (8 bh x 16 chunks)
    const int lin = blockIdx.x;
    const int slot = lin >> 3;
    const int bh = (lin & 7) + 8 * (slot >> 4);
    const int chunk = slot & 15;
    const int b = bh >> 4;
    const int t0w = chunk * 4 + wid;        // this wave's q-tile index
    const int l0 = t0w * 16;

    const __bf16* Qbase = Qh + (size_t)bh * 65536;
    const __bf16* Kbase = Kh + (size_t)bh * 65536;
    const __bf16* Vbase = Vt + (size_t)bh * 65536;
    const int* maskb = mask + b * 1024;
    const __bf16* rlo = relkp + 17408;

    // staging offsets: waves 0,1 stage K (2 x 1KB each), waves 2,3 stage V.
    int gKo[2], lKo[2], gVo[2], lVo[2];
    #pragma unroll
    for (int ii = 0; ii < 2; ++ii) {
        const int chK = (wid & 1) * 128 + ii * 64 + lane;   // 0..255
        const int rK = chK >> 3, pK = chK & 7, gK = pK ^ (rK & 7);
        gKo[ii] = rK * 64 + gK * 8;
        lKo[ii] = chK * 8;
        const int chV = (wid & 1) * 128 + ii * 64 + lane;
        const int dV = chV >> 2, pV = chV & 3, gV = pV ^ ((dV >> 1) & 3);
        gVo[ii] = dV * 32 + gV * 8;
        lVo[ii] = chV * 8;
    }

    #define STAGE(t, buf)                                                     \
        do {                                                                  \
            if (wid < 2) {                                                    \
                async16(Kbase + (t) * 2048 + gKo[0], &Ks[buf][0] + lKo[0]);   \
                async16(Kbase + (t) * 2048 + gKo[1], &Ks[buf][0] + lKo[1]);   \
            } else {                                                          \
                async16(Vbase + (t) * 2048 + gVo[0], &Vs[buf][0] + lVo[0]);   \
                async16(Vbase + (t) * 2048 + gVo[1], &Vs[buf][0] + lVo[1]);   \
            }                                                                 \
        } while (0)

    // prologue: stage pairs 0 and 1 (latency hides under mask/c0c1 prologue).
    STAGE(0, 0);
    STAGE(1, 1);

    // mask -> madd_sb (coalesced, once per block; removes in-loop global
    // loads whose in-order vmcnt retirement drained the staged prefetches)
    {
        const int4 mv = *(const int4*)(maskb + tid * 4);
        madd_sb[tid * 4 + 0] = mv.x ? (__bf16)0.f : (__bf16)-1.0e9f;
        madd_sb[tid * 4 + 1] = mv.y ? (__bf16)0.f : (__bf16)-1.0e9f;
        madd_sb[tid * 4 + 2] = mv.z ? (__bf16)0.f : (__bf16)-1.0e9f;
        madd_sb[tid * 4 + 3] = mv.w ? (__bf16)0.f : (__bf16)-1.0e9f;
    }

    const bf16x8_t aq0 = *(const bf16x8_t*)(Qbase + (l0 + l15) * 64 + quad * 8);
    const bf16x8_t aq1 = *(const bf16x8_t*)(Qbase + (l0 + l15) * 64 + 32 + quad * 8);

    // c0/c1 via MFMA: B cols 0/1 hold relk rows 0/256 (hi+lo) -> shfl bcast.
    float c0[4], c1[4];
    {
        const int jr = (l15 == 1) ? 256 : 0;
        const bf16x8_t bh0 = *(const bf16x8_t*)(relkp + jr * 64 + quad * 8);
        const bf16x8_t bh1 = *(const bf16x8_t*)(relkp + jr * 64 + 32 + quad * 8);
        const bf16x8_t bl0 = *(const bf16x8_t*)(rlo + jr * 64 + quad * 8);
        const bf16x8_t bl1 = *(const bf16x8_t*)(rlo + jr * 64 + 32 + quad * 8);
        f32x4_t cr = (f32x4_t){0.f, 0.f, 0.f, 0.f};
        cr = MFMA16(aq0, bl0, cr);
        cr = MFMA16(aq1, bl1, cr);
        cr = MFMA16(aq0, bh0, cr);
        cr = MFMA16(aq1, bh1, cr);
        #pragma unroll
        for (int v = 0; v < 4; ++v) {
            c0[v] = __shfl(cr[v], (lane & 48), 64);
            c1[v] = __shfl(cr[v], (lane & 48) | 1, 64);
        }
    }

    {   // zero own w_s (512 uint4 per wave; per-wave, no barrier needed)
        uint4* wz = (uint4*)&w_s[wid][0][0];
        for (int t = lane; t < 512; t += 64) wz[t] = (uint4){0u, 0u, 0u, 0u};
    }

    f32x4_t o[4];
    #pragma unroll
    for (int dt = 0; dt < 4; ++dt) o[dt] = (f32x4_t){0.f, 0.f, 0.f, 0.f};
    float rowsum[4] = {0.f, 0.f, 0.f, 0.f};
    float e0[4] = {0.f, 0.f, 0.f, 0.f};
    float e1[4] = {0.f, 0.f, 0.f, 0.f};
    f32x4_t qb_carry = (f32x4_t){0.f, 0.f, 0.f, 0.f};

    __syncthreads();   // pc=0/1 staged & drained; madd_sb/w_s visible

    for (int pc = 0; pc < 32; ++pc) {
        // own stage pc landed (2 newer ops = stage pc+1); last iter: drain.
        if (pc < 31) asm volatile("s_waitcnt vmcnt(2)" ::: "memory");
        else         asm volatile("s_waitcnt vmcnt(0)" ::: "memory");
        asm volatile("" ::: "memory");
        __builtin_amdgcn_s_barrier();       // cross-wave: K and V of pc visible
        asm volatile("" ::: "memory");
        if (pc + 2 < 32) STAGE(pc + 2, (pc + 2) % 3);   // overwrites buf of pc-1

        __builtin_amdgcn_s_setprio(1);
        const int cur = pc % 3;
        const int rb0 = pc * 32;
        const int tI0 = pc * 2;
        #pragma unroll
        for (int sl = 0; sl < 2; ++sl) {
            const int tI = tI0 + sl;
            const int dist = tI - t0w;
            const int R = sl * 16 + l15;
            const bf16x8_t kb0 =
                *(const bf16x8_t*)(&Ks[cur][0] + R * 64 + (quad ^ (R & 7)) * 8);
            const bf16x8_t kb1 =
                *(const bf16x8_t*)(&Ks[cur][0] + R * 64 + (((quad + 4) ^ (R & 7))) * 8);
            f32x4_t s = (f32x4_t){0.f, 0.f, 0.f, 0.f};
            s = MFMA16(aq0, kb0, s);
            s = MFMA16(aq1, kb1, s);
            const float madd = (float)madd_sb[rb0 + R];

            if (dist <= -9 || dist >= 9) {      // FAR tile: fully clipped bias
                const bool isLo = dist < 0;
                #pragma unroll
                for (int v = 0; v < 4; ++v) {
                    const float cc = isLo ? c0[v] : c1[v];
                    const float p = __expf(fmaf(s[v], SCALE, cc) + madd);
                    const __bf16 pb = (__bf16)p;
                    const float pf = (float)pb;
                    rowsum[v] += pf;
                    if (isLo) e0[v] += pf; else e1[v] += pf;
                    p_s[wid][quad * 4 + v][sl * 16 + l15] = pb;
                }
            } else {                            // BAND tile: on-the-fly bias
                const int base = dist * 16 + 128;          // 0..256
                // qbA: cols base-15..base (carried from prev slot's qbB when
                // the previous slot was also band); qbB: cols base+1..base+16.
                f32x4_t qbA;
                const bool seed = (dist == -8) || (tI == 0);
                if (seed) {
                    int ra = base - 15 + l15;              // -15..271
                    ra = ra < 0 ? 0 : (ra > 256 ? 256 : ra);
                    const bf16x8_t hA0 = *(const bf16x8_t*)(relkp + ra * 64 + quad * 8);
                    const bf16x8_t hA1 = *(const bf16x8_t*)(relkp + ra * 64 + 32 + quad * 8);
                    const bf16x8_t lA0 = *(const bf16x8_t*)(rlo + ra * 64 + quad * 8);
                    const bf16x8_t lA1 = *(const bf16x8_t*)(rlo + ra * 64 + 32 + quad * 8);
                    qbA = (f32x4_t){0.f, 0.f, 0.f, 0.f};
                    qbA = MFMA16(aq0, lA0, qbA);
                    qbA = MFMA16(aq1, lA1, qbA);
                    qbA = MFMA16(aq0, hA0, qbA);
                    qbA = MFMA16(aq1, hA1, qbA);
                } else {
                    qbA = qb_carry;
                }
                int rb2 = base + 1 + l15;                  // 1..272
                rb2 = rb2 > 256 ? 256 : rb2;
                const bf16x8_t hB0 = *(const bf16x8_t*)(relkp + rb2 * 64 + quad * 8);
                const bf16x8_t hB1 = *(const bf16x8_t*)(relkp + rb2 * 64 + 32 + quad * 8);
                const bf16x8_t lB0 = *(const bf16x8_t*)(rlo + rb2 * 64 + quad * 8);
                const bf16x8_t lB1 = *(const bf16x8_t*)(rlo + rb2 * 64 + 32 + quad * 8);
                f32x4_t qbB = (f32x4_t){0.f, 0.f, 0.f, 0.f};
                qbB = MFMA16(aq0, lB0, qbB);
                qbB = MFMA16(aq1, lB1, qbB);
                qbB = MFMA16(aq0, hB0, qbB);
                qbB = MFMA16(aq1, hB1, qbB);
                qb_carry = qbB;
                #pragma unroll
                for (int v = 0; v < 4; ++v) {
                    const int lrow = quad * 4 + v;
                    const int c = l15 + 15 - lrow;          // 0..30
                    const int src = (lane & 48) | (c & 15);
                    const float bA = __shfl(qbA[v], src, 64);
                    const float bB = __shfl(qbB[v], src, 64);
                    const float qbv = (c & 16) ? bB : bA;
                    const int j = base + l15 - lrow;        // -15..271
                    const float bias = (j < 0) ? c0[v] : ((j > 256) ? c1[v] : qbv);
                    const float p = __expf(fmaf(s[v], SCALE, bias) + madd);
                    const __bf16 pb = (__bf16)p;
                    const float pf = (float)pb;
                    rowsum[v] += pf;
                    p_s[wid][lrow][sl * 16 + l15] = pb;
                    if (j <= 0)        e0[v] += pf;
                    else if (j >= 256) e1[v] += pf;
                    else               w_s[wid][lrow][j] = pb;
                }
            }
        }
        // PV over the 32-row pair
        const bf16x8_t pa = *(const bf16x8_t*)(&p_s[wid][l15][quad * 8]);
        #pragma unroll
        for (int dt = 0; dt < 4; ++dt) {
            const int D = dt * 16 + l15;
            const bf16x8_t vb =
                *(const bf16x8_t*)(&Vs[cur][0] + D * 32 + ((quad ^ ((D >> 1) & 3))) * 8);
            o[dt] = MFMA16(pa, vb, o[dt]);
        }
        __builtin_amdgcn_s_setprio(0);
    }
    #undef STAGE

    // w @ rel_v over cols 0..255 (col 0 stays zero; e0/e1 applied in epilogue)
    for (int kc = 0; kc < 8; ++kc) {
        const bf16x8_t wa = *(const bf16x8_t*)(&w_s[wid][l15][kc * 32 + quad * 8]);
        #pragma unroll
        for (int dt = 0; dt < 4; ++dt) {
            const bf16x8_t rb =
                *(const bf16x8_t*)(rvT + (dt * 16 + l15) * 288 + kc * 32 + quad * 8);
            o[dt] = MFMA16(wa, rb, o[dt]);
        }
    }

    // reduce scalar partials across the 16 lanes of each quad
    #pragma unroll
    for (int v = 0; v < 4; ++v) {
        #pragma unroll
        for (int mm = 1; mm < 16; mm <<= 1) {
            rowsum[v] += __shfl_xor(rowsum[v], mm, 64);
            e0[v]     += __shfl_xor(e0[v], mm, 64);
            e1[v]     += __shfl_xor(e1[v], mm, 64);
        }
    }

    float rinv[4];
    #pragma unroll
    for (int v = 0; v < 4; ++v)
        rinv[v] = 1.f / rowsum[v];
    const int h = bh & 15;
    #pragma unroll
    for (int dt = 0; dt < 4; ++dt) {
        const int d = dt * 16 + l15;
        const float rv0   = relv[d];
        const float rv256 = relv[256 * 64 + d];
        #pragma unroll
        for (int v = 0; v < 4; ++v) {
            const int lrow = quad * 4 + v;
            const float val = (o[dt][v] + e0[v] * rv0 + e1[v] * rv256) * rinv[v];
            ctx[((size_t)b * 1024 + l0 + lrow) * 1024 + h * 64 + d] = (__bf16)val;
        }
    }
}

// ---------------------------------------------------------------------------
extern "C" void kernel_launch(void* const* d_in, const int* in_sizes, int n_in,
                              void* d_out, int out_size, void* d_ws, size_t ws_size,
                              hipStream_t stream)
{
    const float* q    = (const float*)d_in[0];
    const float* k    = (const float*)d_in[1];
    const float* v    = (const float*)d_in[2];
    const int*   mask = (const int*)  d_in[3];
    const float* wq   = (const float*)d_in[4];
    const float* bq   = (const float*)d_in[5];
    const float* wk   = (const float*)d_in[6];
    const float* bk   = (const float*)d_in[7];
    const float* wv   = (const float*)d_in[8];
    const float* bv   = (const float*)d_in[9];
    const float* wo   = (const float*)d_in[10];
    const float* bo   = (const float*)d_in[11];
    const float* relk = (const float*)d_in[12];
    const float* relv = (const float*)d_in[13];

    // workspace layout (bf16 elements unless noted); ~70 MB used.
    __bf16* Xbf   = (__bf16*)d_ws;            // 12582912 (q,k,v inputs hi)
    __bf16* Xgap  = Xbf   + 12582912;         // 4194304 (dead pad)
    __bf16* Wqlo  = Xgap  + 4194304;          // 1048576 (wq residual)
    __bf16* Wall  = Wqlo  + 1048576;          // 4194304 (wq,wk,wv,wo hi)
    __bf16* QKVh  = Wall  + 4194304;          // 12582912 (Q, K, V pair-tiled)
    __bf16* ctx   = QKVh  + 12582912;         // 4194304
    __bf16* relkp = ctx   + 4194304;          // 34816 (hi | lo)
    __bf16* rvT   = relkp + 34816;            // 18432

    cast_all_kernel<<<16419, 256, 0, stream>>>(q, k, v, wq, wk, wv, wo, relk, relv,
                                               Xbf, Wall, relkp, rvT, Wqlo);
    gemm_qkv_kernel<<<dim3(8, 32, 3), 256, 0, stream>>>(Xbf, Wall, Wqlo,
                                                        bq, bk, bv, QKVh);
    attn_fused_kernel<<<1024, 256, 0, stream>>>(QKVh, QKVh + 4194304,
                                                QKVh + 2 * 4194304, relkp,
                                                rvT, mask, relv, ctx);
    gemm_out_kernel<<<dim3(8, 32, 1), 256, 0, stream>>>(ctx, Wall + 3 * 1048576,
                                                        bo, (float*)d_out);
}